// Round 1
// baseline (622.008 us; speedup 1.0000x reference)
//
#include <hip/hip_runtime.h>
#include <hip/hip_bf16.h>

#define NROWS 8192
#define DIM 128

typedef short short8 __attribute__((ext_vector_type(8)));
typedef float f32x4 __attribute__((ext_vector_type(4)));

__device__ __forceinline__ unsigned short bf16r(float f) {
  unsigned int u = __builtin_bit_cast(unsigned int, f);
  u += 0x7fffu + ((u >> 16) & 1u);   // round-to-nearest-even
  return (unsigned short)(u >> 16);
}
__device__ __forceinline__ short8 asbf8(uint4 v) { return __builtin_bit_cast(short8, v); }

// ------------------------- QKV projection (f32) -------------------------
// qkv = x @ W^T + b ; writes Q,K row-major bf16 and V transposed (Vt[d][n]).
__global__ __launch_bounds__(256) void qkv_proj(
    const float* __restrict__ x, const float* __restrict__ W, const float* __restrict__ bias,
    unsigned short* __restrict__ Q, unsigned short* __restrict__ K, unsigned short* __restrict__ Vt)
{
  __shared__ float sX[64 * 132];          // 64 rows x 128, pad to 132 (bank spread)
  const int rt = blockIdx.x;              // 128 row tiles of 64
  const int ct = blockIdx.y;              // 6 col tiles of 64 (0,1->Q 2,3->K 4,5->V)
  const int t = threadIdx.x;

  const float4* xg = (const float4*)(x + (size_t)rt * 64 * DIM);
#pragma unroll
  for (int j = 0; j < 8; j++) {
    int i = t + 256 * j;                  // 2048 float4 = 64x128 floats
    int row = i >> 5, c4 = i & 31;
    *(float4*)&sX[row * 132 + c4 * 4] = xg[i];
  }
  __syncthreads();

  const int tx = t & 15, ty = t >> 4;
  const int c0 = ct * 64 + tx * 4;
  float acc[4][4] = {};
#pragma unroll
  for (int kc = 0; kc < 8; kc++) {        // k chunks of 16
    float4 wr[4][4];
#pragma unroll
    for (int j = 0; j < 4; j++)
#pragma unroll
      for (int u = 0; u < 4; u++)
        wr[j][u] = *(const float4*)(W + (size_t)(c0 + j) * DIM + kc * 16 + u * 4);
#pragma unroll
    for (int i = 0; i < 4; i++) {
      float4 xv[4];
#pragma unroll
      for (int u = 0; u < 4; u++) xv[u] = *(const float4*)&sX[(ty * 4 + i) * 132 + kc * 16 + u * 4];
#pragma unroll
      for (int j = 0; j < 4; j++) {
        float s = acc[i][j];
#pragma unroll
        for (int u = 0; u < 4; u++) {
          s = fmaf(xv[u].x, wr[j][u].x, s);
          s = fmaf(xv[u].y, wr[j][u].y, s);
          s = fmaf(xv[u].z, wr[j][u].z, s);
          s = fmaf(xv[u].w, wr[j][u].w, s);
        }
        acc[i][j] = s;
      }
    }
  }
#pragma unroll
  for (int i = 0; i < 4; i++) {
    int row = rt * 64 + ty * 4 + i;
#pragma unroll
    for (int j = 0; j < 4; j++) {
      int c = c0 + j;
      unsigned short h = bf16r(acc[i][j] + bias[c]);
      if (c < 128)      Q[(size_t)row * DIM + c] = h;
      else if (c < 256) K[(size_t)row * DIM + (c - 128)] = h;
      else              Vt[(size_t)(c - 256) * NROWS + row] = h;
    }
  }
}

// ------------------------- flash attention (bf16 MFMA) -------------------------
// Block: 4 waves x 16 q-rows. KV tile 64, LDS-staged, XOR-swizzled.
// S-frag: mfma(A=Q[16x32d], B=K^T) ; acc lane l holds S[q=4*(l>>4)+reg][k=l&15].
// P transposed through per-wave LDS; PV: mfma(A=P[16x32k], B=V via Vt rows).
__global__ __launch_bounds__(256) void attn(
    const unsigned short* __restrict__ Q, const unsigned short* __restrict__ K,
    const unsigned short* __restrict__ Vt,
    float* __restrict__ Op, float* __restrict__ Mp, float* __restrict__ Lp,
    float* __restrict__ outDirect, int kvlen)
{
  __shared__ uint4 sKu[64 * 16];               // K tile [64][128] bf16, swizzled
  __shared__ uint4 sVu[128 * 8];               // Vt tile [128][64] bf16, swizzled
  __shared__ unsigned short sP[4][16][72];     // per-wave P transpose buffer

  const int t = threadIdx.x;
  const int w = t >> 6, l = t & 63;
  const int r = l & 15, g = l >> 4;
  const int qt = blockIdx.x, sp = blockIdx.y;
  const int qbase = qt * 64 + w * 16;

  uint4 qf[4];
  {
    const uint4* Qv = (const uint4*)(Q + (size_t)(qbase + r) * DIM);
#pragma unroll
    for (int f = 0; f < 4; f++) qf[f] = Qv[f * 4 + g];
  }

  float m_[4], l_[4];
#pragma unroll
  for (int i = 0; i < 4; i++) { m_[i] = -1e30f; l_[i] = 0.f; }
  f32x4 oacc[8];
#pragma unroll
  for (int dc = 0; dc < 8; dc++) oacc[dc] = (f32x4){0.f, 0.f, 0.f, 0.f};

  const int kb0 = sp * kvlen;
  for (int kb = kb0; kb < kb0 + kvlen; kb += 64) {
    __syncthreads();   // protect LDS from previous iteration's readers
#pragma unroll
    for (int j = 0; j < 4; j++) {
      int i = t + 256 * j;                       // 1024 uint4 each
      { int krow = i >> 4, c16 = i & 15;
        sKu[krow * 16 + (c16 ^ (krow & 7))] =
            ((const uint4*)(K + (size_t)(kb + krow) * DIM))[c16]; }
      { int vrow = i >> 3, c16 = i & 7;
        sVu[vrow * 8 + (c16 ^ (vrow & 7))] =
            ((const uint4*)(Vt + (size_t)vrow * NROWS + kb))[c16]; }
    }
    __syncthreads();

    // ---- S = Q K^T for 64 keys (4 x 16-key subtiles) ----
    f32x4 sacc[4];
#pragma unroll
    for (int kc = 0; kc < 4; kc++) {
      f32x4 acc = (f32x4){0.f, 0.f, 0.f, 0.f};
#pragma unroll
      for (int f = 0; f < 4; f++) {
        uint4 kf = sKu[(kc * 16 + r) * 16 + ((f * 4 + g) ^ (r & 7))];
        acc = __builtin_amdgcn_mfma_f32_16x16x32_bf16(asbf8(qf[f]), asbf8(kf), acc, 0, 0, 0);
      }
      sacc[kc] = acc;
    }

    // ---- online softmax ----
    float rmax[4], rsum[4], alpha[4];
#pragma unroll
    for (int reg = 0; reg < 4; reg++) {
      float v = fmaxf(fmaxf(sacc[0][reg], sacc[1][reg]), fmaxf(sacc[2][reg], sacc[3][reg]));
#pragma unroll
      for (int off = 1; off < 16; off <<= 1) v = fmaxf(v, __shfl_xor(v, off));
      rmax[reg] = v;
    }
#pragma unroll
    for (int reg = 0; reg < 4; reg++) {
      float mn = fmaxf(m_[reg], rmax[reg]);
      alpha[reg] = __expf(m_[reg] - mn);
      m_[reg] = mn;
      rsum[reg] = 0.f;
    }
#pragma unroll
    for (int kc = 0; kc < 4; kc++)
#pragma unroll
      for (int reg = 0; reg < 4; reg++) {
        float p = __expf(sacc[kc][reg] - m_[reg]);
        rsum[reg] += p;
        sP[w][4 * g + reg][kc * 16 + r] = bf16r(p);
      }
#pragma unroll
    for (int reg = 0; reg < 4; reg++) {
      float v = rsum[reg];
#pragma unroll
      for (int off = 1; off < 16; off <<= 1) v += __shfl_xor(v, off);
      l_[reg] = l_[reg] * alpha[reg] + v;
    }
#pragma unroll
    for (int dc = 0; dc < 8; dc++) {
      f32x4 o = oacc[dc];
      o[0] *= alpha[0]; o[1] *= alpha[1]; o[2] *= alpha[2]; o[3] *= alpha[3];
      oacc[dc] = o;
    }

    // ---- read P back in A-fragment layout (wave-private, no barrier) ----
    uint4 pf[2];
    {
      const uint4* prow = (const uint4*)&sP[w][r][0];  // row stride 144B, 16B aligned
      pf[0] = prow[g];
      pf[1] = prow[4 + g];
    }
    // ---- O += P V ----
#pragma unroll
    for (int dc = 0; dc < 8; dc++)
#pragma unroll
      for (int ka = 0; ka < 2; ka++) {
        uint4 vf = sVu[(dc * 16 + r) * 8 + ((ka * 4 + g) ^ (r & 7))];
        oacc[dc] = __builtin_amdgcn_mfma_f32_16x16x32_bf16(asbf8(pf[ka]), asbf8(vf), oacc[dc], 0, 0, 0);
      }
  }

  // ---- epilogue ----
  if (outDirect) {
#pragma unroll
    for (int reg = 0; reg < 4; reg++) {
      float inv = 1.f / l_[reg];
      int q = qbase + 4 * g + reg;
      float* po = outDirect + (size_t)q * DIM + r;
#pragma unroll
      for (int dc = 0; dc < 8; dc++) po[dc * 16] = oacc[dc][reg] * inv;
    }
  } else {
#pragma unroll
    for (int reg = 0; reg < 4; reg++) {
      int q = qbase + 4 * g + reg;
      float* po = Op + ((size_t)sp * NROWS + q) * DIM + r;
#pragma unroll
      for (int dc = 0; dc < 8; dc++) po[dc * 16] = oacc[dc][reg];
      if (r == 0) {
        Mp[(size_t)sp * NROWS + q] = m_[reg];
        Lp[(size_t)sp * NROWS + q] = l_[reg];
      }
    }
  }
}

// ------------------------- KV-split combine -------------------------
__global__ __launch_bounds__(256) void combine(
    const float* __restrict__ Op, const float* __restrict__ Mp, const float* __restrict__ Lp,
    float* __restrict__ out, int S)
{
  int gid = blockIdx.x * 256 + threadIdx.x;
  int q = gid >> 7, d = gid & 127;
  float M = -1e30f;
  for (int s = 0; s < S; s++) M = fmaxf(M, Mp[(size_t)s * NROWS + q]);
  float num = 0.f, den = 0.f;
  for (int s = 0; s < S; s++) {
    float e = __expf(Mp[(size_t)s * NROWS + q] - M);
    den = fmaf(e, Lp[(size_t)s * NROWS + q], den);
    num = fmaf(e, Op[((size_t)s * NROWS + q) * DIM + d], num);
  }
  out[gid] = num / den;
  (void)d;
}

// ------------------------- launcher -------------------------
extern "C" void kernel_launch(void* const* d_in, const int* in_sizes, int n_in,
                              void* d_out, int out_size, void* d_ws, size_t ws_size,
                              hipStream_t stream)
{
  (void)in_sizes; (void)n_in; (void)out_size;
  const float* x = (const float*)d_in[0];
  const float* W = (const float*)d_in[1];
  const float* b = (const float*)d_in[2];
  float* out = (float*)d_out;
  char* ws = (char*)d_ws;

  unsigned short* Q  = (unsigned short*)ws;
  unsigned short* K  = Q + (size_t)NROWS * DIM;
  unsigned short* Vt = K + (size_t)NROWS * DIM;
  const size_t qkvB = (size_t)3 * NROWS * DIM * 2;   // 6,291,456 B

  auto need = [&](int S) {
    return qkvB + (size_t)S * NROWS * DIM * 4 + (size_t)S * NROWS * 8;
  };
  int S; bool direct = false;
  if      (ws_size >= need(4)) S = 4;
  else if (ws_size >= need(2)) S = 2;
  else if (ws_size >= need(1)) S = 1;
  else { S = 1; direct = true; }

  float* Op = (float*)(ws + qkvB);
  float* Mp = Op + (size_t)S * NROWS * DIM;
  float* Lp = Mp + (size_t)S * NROWS;

  qkv_proj<<<dim3(128, 6), 256, 0, stream>>>(x, W, b, Q, K, Vt);
  attn<<<dim3(128, S), 256, 0, stream>>>(Q, K, Vt, Op, Mp, Lp,
                                         direct ? out : nullptr, NROWS / S);
  if (!direct) combine<<<4096, 256, 0, stream>>>(Op, Mp, Lp, out, S);
}

// Round 2
// 167.526 us; speedup vs baseline: 3.7129x; 3.7129x over previous
//
#include <hip/hip_runtime.h>
#include <hip/hip_bf16.h>

#define NROWS 8192
#define DIM 128

typedef short short8 __attribute__((ext_vector_type(8)));
typedef float f32x4 __attribute__((ext_vector_type(4)));
typedef unsigned short ushort4v __attribute__((ext_vector_type(4)));

__device__ __forceinline__ unsigned short bf16r(float f) {
  unsigned int u = __builtin_bit_cast(unsigned int, f);
  u += 0x7fffu + ((u >> 16) & 1u);   // round-to-nearest-even
  return (unsigned short)(u >> 16);
}
__device__ __forceinline__ short8 asbf8(uint4 v) { return __builtin_bit_cast(short8, v); }

// ------------------------- QKV projection (f32, LDS-staged) -------------------------
// qkv = x @ W^T + b ; writes Q,K row-major bf16 and V transposed (Vt[d][n]).
// 64x64 tile, 4x4 micro-tile/thread. V goes through an LDS transpose so the
// Vt store is 32B-contiguous per lane (no 2B scatter).
__global__ __launch_bounds__(256) void qkv_proj(
    const float* __restrict__ x, const float* __restrict__ W, const float* __restrict__ bias,
    unsigned short* __restrict__ Q, unsigned short* __restrict__ K, unsigned short* __restrict__ Vt)
{
  __shared__ float sX[64 * 132];            // 64 rows x 128, pad->132 (2-way conflicts only)
  __shared__ float sW[64 * 132];
  __shared__ unsigned short sT[64 * 72];    // V transpose buffer [d_local][row_local]

  const int rt = blockIdx.x;                // 128 row tiles of 64
  const int ct = blockIdx.y;                // 6 col tiles of 64 (0,1->Q 2,3->K 4,5->V)
  const int t = threadIdx.x;

  const float4* xg = (const float4*)(x + (size_t)rt * 64 * DIM);
  const float4* wg = (const float4*)(W + (size_t)ct * 64 * DIM);
#pragma unroll
  for (int j = 0; j < 8; j++) {
    int i = t + 256 * j;                    // 2048 float4 = 64x128 floats
    int row = i >> 5, c4 = i & 31;
    *(float4*)&sX[row * 132 + c4 * 4] = xg[i];
    *(float4*)&sW[row * 132 + c4 * 4] = wg[i];
  }
  __syncthreads();

  const int tx = t & 15, ty = t >> 4;
  const int c0 = ct * 64 + tx * 4;

  float acc[4][4] = {};
#pragma unroll 8
  for (int k4 = 0; k4 < 32; k4++) {         // k in chunks of 4
    float4 xv[4], wv[4];
#pragma unroll
    for (int i = 0; i < 4; i++) xv[i] = *(const float4*)&sX[(ty * 4 + i) * 132 + k4 * 4];
#pragma unroll
    for (int j = 0; j < 4; j++) wv[j] = *(const float4*)&sW[(tx * 4 + j) * 132 + k4 * 4];
#pragma unroll
    for (int i = 0; i < 4; i++)
#pragma unroll
      for (int j = 0; j < 4; j++) {
        float s = acc[i][j];
        s = fmaf(xv[i].x, wv[j].x, s);
        s = fmaf(xv[i].y, wv[j].y, s);
        s = fmaf(xv[i].z, wv[j].z, s);
        s = fmaf(xv[i].w, wv[j].w, s);
        acc[i][j] = s;
      }
  }

  float bv[4];
#pragma unroll
  for (int j = 0; j < 4; j++) bv[j] = bias[c0 + j];

  if (ct < 4) {
    // Q or K: pack 4 contiguous bf16 -> 8B store per row
    unsigned short* dst = (ct < 2) ? Q : K;
    const int cc = (ct < 2) ? c0 : c0 - 128;
#pragma unroll
    for (int i = 0; i < 4; i++) {
      int row = rt * 64 + ty * 4 + i;
      ushort4v h;
#pragma unroll
      for (int j = 0; j < 4; j++) h[j] = bf16r(acc[i][j] + bv[j]);
      *(ushort4v*)&dst[(size_t)row * DIM + cc] = h;
    }
  } else {
    // V: transpose via LDS, then 32B-contiguous stores into Vt[d][n]
#pragma unroll
    for (int i = 0; i < 4; i++)
#pragma unroll
      for (int j = 0; j < 4; j++)
        sT[(tx * 4 + j) * 72 + ty * 4 + i] = bf16r(acc[i][j] + bv[j]);
    __syncthreads();
    const int dl = t & 63, chunk = t >> 6;        // 64 d x 4 chunks of 16 rows
    const int dg = (ct - 4) * 64 + dl;
    uint4* dst = (uint4*)(Vt + (size_t)dg * NROWS + rt * 64 + chunk * 16);
    const uint4* src = (const uint4*)&sT[dl * 72 + chunk * 16];
    dst[0] = src[0];
    dst[1] = src[1];
  }
}

// ------------------------- flash attention (bf16 MFMA) -------------------------
// Block: 4 waves x 16 q-rows. KV tile 64, LDS-staged, XOR-swizzled.
// S-frag: mfma(A=Q[16x32d], B=K^T) ; acc lane l holds S[q=4*(l>>4)+reg][k=l&15].
// P transposed through per-wave LDS; PV: mfma(A=P[16x32k], B=V via Vt rows).
__global__ __launch_bounds__(256) void attn(
    const unsigned short* __restrict__ Q, const unsigned short* __restrict__ K,
    const unsigned short* __restrict__ Vt,
    float* __restrict__ Op, float* __restrict__ Mp, float* __restrict__ Lp,
    float* __restrict__ outDirect, int kvlen)
{
  __shared__ uint4 sKu[64 * 16];               // K tile [64][128] bf16, swizzled
  __shared__ uint4 sVu[128 * 8];               // Vt tile [128][64] bf16, swizzled
  __shared__ unsigned short sP[4][16][72];     // per-wave P transpose buffer

  const int t = threadIdx.x;
  const int w = t >> 6, l = t & 63;
  const int r = l & 15, g = l >> 4;
  const int qt = blockIdx.x, sp = blockIdx.y;
  const int qbase = qt * 64 + w * 16;

  uint4 qf[4];
  {
    const uint4* Qv = (const uint4*)(Q + (size_t)(qbase + r) * DIM);
#pragma unroll
    for (int f = 0; f < 4; f++) qf[f] = Qv[f * 4 + g];
  }

  float m_[4], l_[4];
#pragma unroll
  for (int i = 0; i < 4; i++) { m_[i] = -1e30f; l_[i] = 0.f; }
  f32x4 oacc[8];
#pragma unroll
  for (int dc = 0; dc < 8; dc++) oacc[dc] = (f32x4){0.f, 0.f, 0.f, 0.f};

  const int kb0 = sp * kvlen;
  for (int kb = kb0; kb < kb0 + kvlen; kb += 64) {
    __syncthreads();   // protect LDS from previous iteration's readers
#pragma unroll
    for (int j = 0; j < 4; j++) {
      int i = t + 256 * j;                       // 1024 uint4 each
      { int krow = i >> 4, c16 = i & 15;
        sKu[krow * 16 + (c16 ^ (krow & 7))] =
            ((const uint4*)(K + (size_t)(kb + krow) * DIM))[c16]; }
      { int vrow = i >> 3, c16 = i & 7;
        sVu[vrow * 8 + (c16 ^ (vrow & 7))] =
            ((const uint4*)(Vt + (size_t)vrow * NROWS + kb))[c16]; }
    }
    __syncthreads();

    // ---- S = Q K^T for 64 keys (4 x 16-key subtiles) ----
    f32x4 sacc[4];
#pragma unroll
    for (int kc = 0; kc < 4; kc++) {
      f32x4 acc = (f32x4){0.f, 0.f, 0.f, 0.f};
#pragma unroll
      for (int f = 0; f < 4; f++) {
        uint4 kf = sKu[(kc * 16 + r) * 16 + ((f * 4 + g) ^ (r & 7))];
        acc = __builtin_amdgcn_mfma_f32_16x16x32_bf16(asbf8(qf[f]), asbf8(kf), acc, 0, 0, 0);
      }
      sacc[kc] = acc;
    }

    // ---- online softmax ----
    float rmax[4], rsum[4], alpha[4];
#pragma unroll
    for (int reg = 0; reg < 4; reg++) {
      float v = fmaxf(fmaxf(sacc[0][reg], sacc[1][reg]), fmaxf(sacc[2][reg], sacc[3][reg]));
#pragma unroll
      for (int off = 1; off < 16; off <<= 1) v = fmaxf(v, __shfl_xor(v, off));
      rmax[reg] = v;
    }
#pragma unroll
    for (int reg = 0; reg < 4; reg++) {
      float mn = fmaxf(m_[reg], rmax[reg]);
      alpha[reg] = __expf(m_[reg] - mn);
      m_[reg] = mn;
      rsum[reg] = 0.f;
    }
#pragma unroll
    for (int kc = 0; kc < 4; kc++)
#pragma unroll
      for (int reg = 0; reg < 4; reg++) {
        float p = __expf(sacc[kc][reg] - m_[reg]);
        rsum[reg] += p;
        sP[w][4 * g + reg][kc * 16 + r] = bf16r(p);
      }
#pragma unroll
    for (int reg = 0; reg < 4; reg++) {
      float v = rsum[reg];
#pragma unroll
      for (int off = 1; off < 16; off <<= 1) v += __shfl_xor(v, off);
      l_[reg] = l_[reg] * alpha[reg] + v;
    }
#pragma unroll
    for (int dc = 0; dc < 8; dc++) {
      f32x4 o = oacc[dc];
      o[0] *= alpha[0]; o[1] *= alpha[1]; o[2] *= alpha[2]; o[3] *= alpha[3];
      oacc[dc] = o;
    }

    // ---- read P back in A-fragment layout (wave-private, no barrier) ----
    uint4 pf[2];
    {
      const uint4* prow = (const uint4*)&sP[w][r][0];  // row stride 144B, 16B aligned
      pf[0] = prow[g];
      pf[1] = prow[4 + g];
    }
    // ---- O += P V ----
#pragma unroll
    for (int dc = 0; dc < 8; dc++)
#pragma unroll
      for (int ka = 0; ka < 2; ka++) {
        uint4 vf = sVu[(dc * 16 + r) * 8 + ((ka * 4 + g) ^ (r & 7))];
        oacc[dc] = __builtin_amdgcn_mfma_f32_16x16x32_bf16(asbf8(pf[ka]), asbf8(vf), oacc[dc], 0, 0, 0);
      }
  }

  // ---- epilogue ----
  if (outDirect) {
#pragma unroll
    for (int reg = 0; reg < 4; reg++) {
      float inv = 1.f / l_[reg];
      int q = qbase + 4 * g + reg;
      float* po = outDirect + (size_t)q * DIM + r;
#pragma unroll
      for (int dc = 0; dc < 8; dc++) po[dc * 16] = oacc[dc][reg] * inv;
    }
  } else {
#pragma unroll
    for (int reg = 0; reg < 4; reg++) {
      int q = qbase + 4 * g + reg;
      float* po = Op + ((size_t)sp * NROWS + q) * DIM + r;
#pragma unroll
      for (int dc = 0; dc < 8; dc++) po[dc * 16] = oacc[dc][reg];
      if (r == 0) {
        Mp[(size_t)sp * NROWS + q] = m_[reg];
        Lp[(size_t)sp * NROWS + q] = l_[reg];
      }
    }
  }
}

// ------------------------- KV-split combine -------------------------
__global__ __launch_bounds__(256) void combine(
    const float* __restrict__ Op, const float* __restrict__ Mp, const float* __restrict__ Lp,
    float* __restrict__ out, int S)
{
  int gid = blockIdx.x * 256 + threadIdx.x;
  int q = gid >> 7, d = gid & 127;
  float M = -1e30f;
  for (int s = 0; s < S; s++) M = fmaxf(M, Mp[(size_t)s * NROWS + q]);
  float num = 0.f, den = 0.f;
  for (int s = 0; s < S; s++) {
    float e = __expf(Mp[(size_t)s * NROWS + q] - M);
    den = fmaf(e, Lp[(size_t)s * NROWS + q], den);
    num = fmaf(e, Op[((size_t)s * NROWS + q) * DIM + d], num);
  }
  out[gid] = num / den;
  (void)d;
}

// ------------------------- launcher -------------------------
extern "C" void kernel_launch(void* const* d_in, const int* in_sizes, int n_in,
                              void* d_out, int out_size, void* d_ws, size_t ws_size,
                              hipStream_t stream)
{
  (void)in_sizes; (void)n_in; (void)out_size;
  const float* x = (const float*)d_in[0];
  const float* W = (const float*)d_in[1];
  const float* b = (const float*)d_in[2];
  float* out = (float*)d_out;
  char* ws = (char*)d_ws;

  unsigned short* Q  = (unsigned short*)ws;
  unsigned short* K  = Q + (size_t)NROWS * DIM;
  unsigned short* Vt = K + (size_t)NROWS * DIM;
  const size_t qkvB = (size_t)3 * NROWS * DIM * 2;   // 6,291,456 B

  auto need = [&](int S) {
    return qkvB + (size_t)S * NROWS * DIM * 4 + (size_t)S * NROWS * 8;
  };
  int S; bool direct = false;
  if      (ws_size >= need(4)) S = 4;
  else if (ws_size >= need(2)) S = 2;
  else if (ws_size >= need(1)) S = 1;
  else { S = 1; direct = true; }

  float* Op = (float*)(ws + qkvB);
  float* Mp = Op + (size_t)S * NROWS * DIM;
  float* Lp = Mp + (size_t)S * NROWS;

  qkv_proj<<<dim3(128, 6), 256, 0, stream>>>(x, W, b, Q, K, Vt);
  attn<<<dim3(128, S), 256, 0, stream>>>(Q, K, Vt, Op, Mp, Lp,
                                         direct ? out : nullptr, NROWS / S);
  if (!direct) combine<<<4096, 256, 0, stream>>>(Op, Mp, Lp, out, S);
}